// Round 3
// baseline (1046.687 us; speedup 1.0000x reference)
//
#include <hip/hip_runtime.h>
#include <math.h>

// Problem constants (fixed by setup_inputs)
#define T_SEQ 2048
#define BATCH 4
#define HDIM  2048
#define NH    16
#define HD    128
#define M_ROWS (BATCH * T_SEQ)                       // 8192
#define QSZ ((size_t)BATCH * NH * T_SEQ * HD)        // 16,777,216 elements

typedef short bf16x8 __attribute__((ext_vector_type(8)));
typedef float f32x4  __attribute__((ext_vector_type(4)));

#define GLOBAL_AS(p) ((const __attribute__((address_space(1))) void*)(p))
#define LDS_AS(p)    ((__attribute__((address_space(3))) void*)(p))

__device__ __forceinline__ unsigned short f2bf(float x) {   // RNE fp32->bf16
    union { float f; unsigned u; } a; a.f = x;
    unsigned r = a.u + 0x7FFFu + ((a.u >> 16) & 1u);
    return (unsigned short)(r >> 16);
}
__device__ __forceinline__ float bf2f(unsigned short b) {
    union { unsigned u; float f; } a; a.u = ((unsigned)b) << 16;
    return a.f;
}

// ---------------------------------------------------------------------------
// RoPE cos/sin table: tab[0 .. T*64) = cos, tab[T*64 .. 2*T*64) = sin
// ---------------------------------------------------------------------------
__global__ void rope_table_kernel(float* __restrict__ tab) {
    int i = blockIdx.x * blockDim.x + threadIdx.x;
    if (i >= T_SEQ * 64) return;
    int t = i >> 6;
    int j = i & 63;
    float inv = expf(-(float)(2 * j) * (1.0f / 128.0f) * logf(10000.0f));
    float ang = (float)t * inv;
    tab[i]              = cosf(ang);
    tab[T_SEQ * 64 + i] = sinf(ang);
}

// ---------------------------------------------------------------------------
// Convert fp32 inputs -> bf16: x -> xb, {Wq,Wk,Wv} -> wcat (row-concat), Wo -> wob
// ---------------------------------------------------------------------------
__global__ void convert_inputs(const float* __restrict__ x,  const float* __restrict__ wq,
                               const float* __restrict__ wk, const float* __restrict__ wv,
                               const float* __restrict__ wo,
                               unsigned short* __restrict__ xb,
                               unsigned short* __restrict__ wcat,
                               unsigned short* __restrict__ wob) {
    const int NX4 = (M_ROWS * HDIM) / 4;   // 4,194,304
    const int NW4 = (HDIM * HDIM) / 4;     // 1,048,576
    int i = blockIdx.x * blockDim.x + threadIdx.x;
    if (i >= NX4 + 4 * NW4) return;
    const float* src; unsigned short* dst; size_t off;
    if (i < NX4)                { src = x;  dst = xb;                      off = i; }
    else if (i < NX4 + NW4)     { src = wq; dst = wcat;                    off = i - NX4; }
    else if (i < NX4 + 2 * NW4) { src = wk; dst = wcat + HDIM * HDIM;      off = (size_t)i - NX4 - NW4; }
    else if (i < NX4 + 3 * NW4) { src = wv; dst = wcat + 2 * HDIM * HDIM;  off = (size_t)i - NX4 - 2 * NW4; }
    else                        { src = wo; dst = wob;                     off = (size_t)i - NX4 - 3 * NW4; }
    float4 v = *(const float4*)(src + 4 * off);
    ushort4 p;
    p.x = f2bf(v.x); p.y = f2bf(v.y); p.z = f2bf(v.z); p.w = f2bf(v.w);
    *(ushort4*)(dst + 4 * off) = p;
}

// ---------------------------------------------------------------------------
// RoPE in-place on bf16 Q,K, layout [B][nH][T][hd]. 4 d-pairs per thread.
// ---------------------------------------------------------------------------
__global__ void rope_bf16(unsigned short* __restrict__ Q, unsigned short* __restrict__ K,
                          const float* __restrict__ tab) {
    int i = blockIdx.x * blockDim.x + threadIdx.x;
    if (i >= BATCH * NH * T_SEQ * 16) return;
    int d4 = (i & 15) << 2;                  // 0..60
    int rrow = i >> 4;                       // over B*nH*T
    int t = rrow & (T_SEQ - 1);
    size_t base = (size_t)rrow * HD + d4;
    float4 c = *(const float4*)&tab[t * 64 + d4];
    float4 s = *(const float4*)&tab[T_SEQ * 64 + t * 64 + d4];

    ushort4 qa = *(ushort4*)&Q[base], qb = *(ushort4*)&Q[base + 64];
    ushort4 ka = *(ushort4*)&K[base], kb = *(ushort4*)&K[base + 64];
    ushort4 oqa, oqb, oka, okb;
    float a0, a1;
#define ROT(vec_a, vec_b, out_a, out_b, comp, cc, ss)                         \
    a0 = bf2f(vec_a.comp); a1 = bf2f(vec_b.comp);                             \
    out_a.comp = f2bf(a0 * cc - a1 * ss);                                     \
    out_b.comp = f2bf(a1 * cc + a0 * ss);
    ROT(qa, qb, oqa, oqb, x, c.x, s.x)  ROT(qa, qb, oqa, oqb, y, c.y, s.y)
    ROT(qa, qb, oqa, oqb, z, c.z, s.z)  ROT(qa, qb, oqa, oqb, w, c.w, s.w)
    ROT(ka, kb, oka, okb, x, c.x, s.x)  ROT(ka, kb, oka, okb, y, c.y, s.y)
    ROT(ka, kb, oka, okb, z, c.z, s.z)  ROT(ka, kb, oka, okb, w, c.w, s.w)
#undef ROT
    *(ushort4*)&Q[base]      = oqa;
    *(ushort4*)&Q[base + 64] = oqb;
    *(ushort4*)&K[base]      = oka;
    *(ushort4*)&K[base + 64] = okb;
}

// ---------------------------------------------------------------------------
// bf16 MFMA NT GEMM (m97 structure): C[M][N] = A[M][K] * W[N][K]^T.
// 128x128 tile, BK=32, 4 waves (2x2), 16x16x32 MFMA, k-octet-major LDS.
// MODE 0: bf16 out, head-split: tensor0/1 (Q,K) -> [b][h][t][d];
//         tensor2 (V) -> TRANSPOSED [b][h][d][t] (ushort4 over t).
// MODE 1: fp32 out, row-major C[M][Ncols].
// ---------------------------------------------------------------------------
template <int MODE>
__global__ void gemm_bf16(const unsigned short* __restrict__ A,
                          const unsigned short* __restrict__ W,
                          void* __restrict__ Cv, int Ncols) {
    __shared__ __align__(16) unsigned short As[4][128][8];
    __shared__ __align__(16) unsigned short Bs[4][128][8];
    const int K = HDIM;
    const int tid = threadIdx.x;
    const int lane = tid & 63;
    const int wid = tid >> 6;
    const int wrow = wid >> 1, wcol = wid & 1;
    const int m0 = blockIdx.y * 128;
    const int n0 = blockIdx.x * 128;

    f32x4 acc[4][4] = {};

    const int rowS0 = tid & 127, ksegS0 = tid >> 7;          // flat = tid
    const unsigned short* gA0 = A + (size_t)(m0 + rowS0) * K + ksegS0 * 8;
    const unsigned short* gA1 = gA0 + 16;                    // flat+256 -> kseg+2
    const unsigned short* gB0 = W + (size_t)(n0 + rowS0) * K + ksegS0 * 8;
    const unsigned short* gB1 = gB0 + 16;
    char* lA0 = (char*)As + (0 * 256 + wid * 64) * 16;
    char* lA1 = (char*)As + (1 * 256 + wid * 64) * 16;
    char* lB0 = (char*)Bs + (0 * 256 + wid * 64) * 16;
    char* lB1 = (char*)Bs + (1 * 256 + wid * 64) * 16;

    const int frag_off = ((lane >> 4) * 128 + (lane & 15)) * 16;
    const char* aF = (const char*)As + frag_off + (wrow * 64) * 16;
    const char* bF = (const char*)Bs + frag_off + (wcol * 64) * 16;

    for (int k0 = 0; k0 < K; k0 += 32) {
        __syncthreads();
        __builtin_amdgcn_global_load_lds(GLOBAL_AS(gA0 + k0), LDS_AS(lA0), 16, 0, 0);
        __builtin_amdgcn_global_load_lds(GLOBAL_AS(gA1 + k0), LDS_AS(lA1), 16, 0, 0);
        __builtin_amdgcn_global_load_lds(GLOBAL_AS(gB0 + k0), LDS_AS(lB0), 16, 0, 0);
        __builtin_amdgcn_global_load_lds(GLOBAL_AS(gB1 + k0), LDS_AS(lB1), 16, 0, 0);
        __syncthreads();

        bf16x8 fa[4], fb[4];
#pragma unroll
        for (int m = 0; m < 4; ++m) fa[m] = *(const bf16x8*)(aF + m * 256);
#pragma unroll
        for (int n = 0; n < 4; ++n) fb[n] = *(const bf16x8*)(bF + n * 256);
#pragma unroll
        for (int m = 0; m < 4; ++m)
#pragma unroll
            for (int n = 0; n < 4; ++n)
                acc[m][n] = __builtin_amdgcn_mfma_f32_16x16x32_bf16(fa[m], fb[n], acc[m][n], 0, 0, 0);
    }

    // epilogue: C/D layout col = lane&15, row = (lane>>4)*4 + r
    const int colBase = n0 + wcol * 64 + (lane & 15);
    const int rowBase = m0 + wrow * 64 + (lane >> 4) * 4;
#pragma unroll
    for (int m = 0; m < 4; ++m) {
        int row0 = rowBase + m * 16;                  // multiple of 4
#pragma unroll
        for (int n = 0; n < 4; ++n) {
            int col = colBase + n * 16;
            if (MODE == 1) {
                float* C = (float*)Cv;
#pragma unroll
                for (int r = 0; r < 4; ++r)
                    C[(size_t)(row0 + r) * Ncols + col] = acc[m][n][r];
            } else {
                unsigned short* Cb = (unsigned short*)Cv;
                int tensor = col >> 11;
                int head = (col >> 7) & 15;
                int d = col & (HD - 1);
                int b = row0 >> 11;
                int t0 = row0 & (T_SEQ - 1);
                if (tensor == 2) {                    // V transposed: [b][h][d][t]
                    ushort4 pv;
                    pv.x = f2bf(acc[m][n][0]); pv.y = f2bf(acc[m][n][1]);
                    pv.z = f2bf(acc[m][n][2]); pv.w = f2bf(acc[m][n][3]);
                    *(ushort4*)&Cb[2 * QSZ + ((size_t)(b * NH + head) * HD + d) * T_SEQ + t0] = pv;
                } else {                              // Q/K: [b][h][t][d]
#pragma unroll
                    for (int r = 0; r < 4; ++r)
                        Cb[(size_t)tensor * QSZ +
                           ((size_t)(b * NH + head) * T_SEQ + (t0 + r)) * HD + d] =
                            f2bf(acc[m][n][r]);
                }
            }
        }
    }
}

// ---------------------------------------------------------------------------
// bf16 MFMA flash attention, causal. Grid (T/64, B*nH), 256 thr = 4 waves (2x2).
// Per block: 64 q rows; kv tiles of 64. Q/K bf16 [b][h][t][d]; V bf16
// TRANSPOSED [b][h][d][t]. Output bf16 merged [b][t][h*128+d].
// Per tile: QK^T MFMA -> Sf32 LDS -> 4-thr/row softmax (online m,l in regs)
// -> P bf16 LDS (k-octet-major) -> rescale+PV MFMA.
// ---------------------------------------------------------------------------
__global__ __launch_bounds__(256, 2) void flash_mfma(
        const unsigned short* __restrict__ Qg, const unsigned short* __restrict__ Kg,
        const unsigned short* __restrict__ Vg, unsigned short* __restrict__ Og) {
    __shared__ __align__(16) unsigned short Qs[16][64][8];   // 16 KB
    __shared__ __align__(16) unsigned short Ks[16][64][8];   // 16 KB
    __shared__ __align__(16) unsigned short Vs[8][128][8];   // 16 KB (V^T tile)
    __shared__ __align__(16) float Sf[64][68];               // 17.4 KB
    __shared__ __align__(16) unsigned short Ps[8][64][8];    // 8 KB
    __shared__ float fac_lds[64];

    const int tid = threadIdx.x;
    const int lane = tid & 63;
    const int wid = tid >> 6;
    const int wr = wid >> 1, wc = wid & 1;
    const int qt = blockIdx.x;
    const int bh = blockIdx.y;
    const int q0 = qt * 64;
    const size_t bho = (size_t)bh * T_SEQ * HD;
    const unsigned short* Qp = Qg + bho + (size_t)q0 * HD;
    const unsigned short* Kp = Kg + bho;
    const unsigned short* Vp = Vg + bho;                     // [d][t]

    // stage Q (64 rows x 128): chunk flat = kseg*64+row
#pragma unroll
    for (int i = 0; i < 4; ++i) {
        int flat = tid + i * 256;
        int row = flat & 63, kseg = flat >> 6;
        __builtin_amdgcn_global_load_lds(GLOBAL_AS(Qp + (size_t)row * HD + kseg * 8),
            LDS_AS((char*)Qs + (i * 256 + wid * 64) * 16), 16, 0, 0);
    }

    f32x4 oacc[2][4] = {};
    float m_run = -3.0e38f, l_run = 0.0f;
    const int srow_my = tid >> 2;   // softmax row 0..63 (4 consecutive lanes/row)
    const int spart = tid & 3;
    const float scale = 0.08838834764831845f;   // 1/sqrt(128)

    for (int kt = 0; kt <= qt; ++kt) {
        const int kv0 = kt * 64;
        __syncthreads();                                     // B0: prev tile done
#pragma unroll
        for (int i = 0; i < 4; ++i) {                        // stage K tile
            int flat = tid + i * 256;
            int row = flat & 63, kseg = flat >> 6;
            __builtin_amdgcn_global_load_lds(GLOBAL_AS(Kp + (size_t)(kv0 + row) * HD + kseg * 8),
                LDS_AS((char*)Ks + (i * 256 + wid * 64) * 16), 16, 0, 0);
        }
#pragma unroll
        for (int i = 0; i < 4; ++i) {                        // stage V^T tile
            int flat = tid + i * 256;
            int d = flat & 127, kseg = flat >> 7;
            __builtin_amdgcn_global_load_lds(GLOBAL_AS(Vp + (size_t)d * T_SEQ + kv0 + kseg * 8),
                LDS_AS((char*)Vs + (i * 256 + wid * 64) * 16), 16, 0, 0);
        }
        __syncthreads();                                     // B1: staging drained

        // QK^T: wave (wr,wc) -> S[wr*32..+32][wc*32..+32]
        f32x4 sacc[2][2] = {};
#pragma unroll
        for (int ks = 0; ks < 4; ++ks) {
            bf16x8 qa[2], kb[2];
#pragma unroll
            for (int m = 0; m < 2; ++m)
                qa[m] = *((const bf16x8*)Qs + ((ks * 4 + (lane >> 4)) * 64 + wr * 32 + m * 16 + (lane & 15)));
#pragma unroll
            for (int n = 0; n < 2; ++n)
                kb[n] = *((const bf16x8*)Ks + ((ks * 4 + (lane >> 4)) * 64 + wc * 32 + n * 16 + (lane & 15)));
#pragma unroll
            for (int m = 0; m < 2; ++m)
#pragma unroll
                for (int n = 0; n < 2; ++n)
                    sacc[m][n] = __builtin_amdgcn_mfma_f32_16x16x32_bf16(qa[m], kb[n], sacc[m][n], 0, 0, 0);
        }

        const bool diag = (kt == qt);
#pragma unroll
        for (int m = 0; m < 2; ++m)
#pragma unroll
            for (int n = 0; n < 2; ++n) {
                int scol = wc * 32 + n * 16 + (lane & 15);
#pragma unroll
                for (int r = 0; r < 4; ++r) {
                    int srw = wr * 32 + m * 16 + (lane >> 4) * 4 + r;
                    float v = sacc[m][n][r] * scale;
                    if (diag && scol > srw) v = -1.0e30f;
                    Sf[srw][scol] = v;
                }
            }
        __syncthreads();                                     // B2

        // softmax: 4 threads per row, in-wave shuffle combine
        float vl[16];
        *(f32x4*)&vl[0]  = *(const f32x4*)&Sf[srow_my][spart * 16];
        *(f32x4*)&vl[4]  = *(const f32x4*)&Sf[srow_my][spart * 16 + 4];
        *(f32x4*)&vl[8]  = *(const f32x4*)&Sf[srow_my][spart * 16 + 8];
        *(f32x4*)&vl[12] = *(const f32x4*)&Sf[srow_my][spart * 16 + 12];
        float pmax = vl[0];
#pragma unroll
        for (int j = 1; j < 16; ++j) pmax = fmaxf(pmax, vl[j]);
        pmax = fmaxf(pmax, __shfl_xor(pmax, 1, 4));
        pmax = fmaxf(pmax, __shfl_xor(pmax, 2, 4));
        float mnew = fmaxf(m_run, pmax);
        float fac = __expf(m_run - mnew);
        float psum = 0.0f;
        unsigned short pb[16];
#pragma unroll
        for (int j = 0; j < 16; ++j) {
            float p = __expf(vl[j] - mnew);
            psum += p;
            pb[j] = f2bf(p);
        }
        // write P: kv index c = spart*16+j; chunk = (c>>3)*64 + row; paired u32
#pragma unroll
        for (int jo = 0; jo < 2; ++jo) {
            int chunk = (spart * 2 + jo) * 64 + srow_my;
            unsigned* dst = (unsigned*)Ps + chunk * 4;
#pragma unroll
            for (int jp = 0; jp < 4; ++jp)
                dst[jp] = (unsigned)pb[jo * 8 + jp * 2] | ((unsigned)pb[jo * 8 + jp * 2 + 1] << 16);
        }
        psum += __shfl_xor(psum, 1, 4);
        psum += __shfl_xor(psum, 2, 4);
        l_run = l_run * fac + psum;
        m_run = mnew;
        if (spart == 0) fac_lds[srow_my] = fac;
        __syncthreads();                                     // B3

        // PV: wave (wr,wc) -> O[wr*32..+32][wc*64..+64]
        float facv[2][4];
#pragma unroll
        for (int m = 0; m < 2; ++m)
#pragma unroll
            for (int r = 0; r < 4; ++r)
                facv[m][r] = fac_lds[wr * 32 + m * 16 + (lane >> 4) * 4 + r];
#pragma unroll
        for (int m = 0; m < 2; ++m)
#pragma unroll
            for (int n = 0; n < 4; ++n)
#pragma unroll
                for (int r = 0; r < 4; ++r)
                    oacc[m][n][r] *= facv[m][r];
#pragma unroll
        for (int ks = 0; ks < 2; ++ks) {
            bf16x8 pa[2], vb[4];
#pragma unroll
            for (int m = 0; m < 2; ++m)
                pa[m] = *((const bf16x8*)Ps + ((ks * 4 + (lane >> 4)) * 64 + wr * 32 + m * 16 + (lane & 15)));
#pragma unroll
            for (int n = 0; n < 4; ++n)
                vb[n] = *((const bf16x8*)Vs + ((ks * 4 + (lane >> 4)) * 128 + wc * 64 + n * 16 + (lane & 15)));
#pragma unroll
            for (int m = 0; m < 2; ++m)
#pragma unroll
                for (int n = 0; n < 4; ++n)
                    oacc[m][n] = __builtin_amdgcn_mfma_f32_16x16x32_bf16(pa[m], vb[n], oacc[m][n], 0, 0, 0);
        }
    }

    // final normalize + write [b][t][h*128+d] bf16
    __syncthreads();
    if (spart == 0) fac_lds[srow_my] = 1.0f / l_run;
    __syncthreads();
    float invv[2][4];
#pragma unroll
    for (int m = 0; m < 2; ++m)
#pragma unroll
        for (int r = 0; r < 4; ++r)
            invv[m][r] = fac_lds[wr * 32 + m * 16 + (lane >> 4) * 4 + r];
    const int b = bh >> 4, h = bh & 15;
#pragma unroll
    for (int m = 0; m < 2; ++m)
#pragma unroll
        for (int n = 0; n < 4; ++n) {
            int d = wc * 64 + n * 16 + (lane & 15);
#pragma unroll
            for (int r = 0; r < 4; ++r) {
                int q = q0 + wr * 32 + m * 16 + (lane >> 4) * 4 + r;
                Og[((size_t)b * T_SEQ + q) * HDIM + h * HD + d] = f2bf(oacc[m][n][r] * invv[m][r]);
            }
        }
}

// ---------------------------------------------------------------------------
// launch
// ---------------------------------------------------------------------------
extern "C" void kernel_launch(void* const* d_in, const int* in_sizes, int n_in,
                              void* d_out, int out_size, void* d_ws, size_t ws_size,
                              hipStream_t stream) {
    const float* x  = (const float*)d_in[0];
    const float* Wq = (const float*)d_in[1];
    const float* Wk = (const float*)d_in[2];
    const float* Wv = (const float*)d_in[3];
    const float* Wo = (const float*)d_in[4];
    float* out = (float*)d_out;

    char* w = (char*)d_ws;
    float* tab = (float*)w;                                        // 1 MB
    unsigned short* xb   = (unsigned short*)(w + (size_t)2 * T_SEQ * 64 * sizeof(float));
    unsigned short* wcat = xb + (size_t)M_ROWS * HDIM;             // [6144][2048]
    unsigned short* wob  = wcat + (size_t)3 * HDIM * HDIM;
    unsigned short* qkv  = wob + (size_t)HDIM * HDIM;              // Q,K [b][h][t][d]; Vt [b][h][d][t]
    unsigned short* aob  = qkv + 3 * QSZ;                          // [8192][2048]

    rope_table_kernel<<<512, 256, 0, stream>>>(tab);

    int nconv = (M_ROWS * HDIM) / 4 + HDIM * HDIM;
    convert_inputs<<<(nconv + 255) / 256, 256, 0, stream>>>(x, Wq, Wk, Wv, Wo, xb, wcat, wob);

    dim3 gqkv(3 * HDIM / 128, M_ROWS / 128);                       // (48, 64)
    gemm_bf16<0><<<gqkv, 256, 0, stream>>>(xb, wcat, (void*)qkv, 3 * HDIM);

    int rtot = BATCH * NH * T_SEQ * 16;
    rope_bf16<<<(rtot + 255) / 256, 256, 0, stream>>>(qkv, qkv + QSZ, tab);

    dim3 fgrid(T_SEQ / 64, BATCH * NH);                            // (32, 64)
    flash_mfma<<<fgrid, 256, 0, stream>>>(qkv, qkv + QSZ, qkv + 2 * QSZ, aob);

    dim3 go(HDIM / 128, M_ROWS / 128);                             // (16, 64)
    gemm_bf16<1><<<go, 256, 0, stream>>>(aob, wob, (void*)out, HDIM);
}

// Round 7
// 718.564 us; speedup vs baseline: 1.4566x; 1.4566x over previous
//
#include <hip/hip_runtime.h>
#include <math.h>

// Problem constants (fixed by setup_inputs)
#define T_SEQ 2048
#define BATCH 4
#define HDIM  2048
#define NH    16
#define HD    128
#define M_ROWS (BATCH * T_SEQ)                       // 8192
#define QSZ ((size_t)BATCH * NH * T_SEQ * HD)        // 16,777,216 elements

typedef short bf16x8 __attribute__((ext_vector_type(8)));
typedef float f32x4  __attribute__((ext_vector_type(4)));

#define GLOBAL_AS(p) ((const __attribute__((address_space(1))) void*)(p))
#define LDS_AS(p)    ((__attribute__((address_space(3))) void*)(p))

__device__ __forceinline__ unsigned short f2bf(float x) {   // RNE fp32->bf16
    union { float f; unsigned u; } a; a.f = x;
    unsigned r = a.u + 0x7FFFu + ((a.u >> 16) & 1u);
    return (unsigned short)(r >> 16);
}
__device__ __forceinline__ float bf2f(unsigned short b) {
    union { unsigned u; float f; } a; a.u = ((unsigned)b) << 16;
    return a.f;
}

// ---------------------------------------------------------------------------
// RoPE cos/sin table: tab[0 .. T*64) = cos, tab[T*64 .. 2*T*64) = sin
// ---------------------------------------------------------------------------
__global__ void rope_table_kernel(float* __restrict__ tab) {
    int i = blockIdx.x * blockDim.x + threadIdx.x;
    if (i >= T_SEQ * 64) return;
    int t = i >> 6;
    int j = i & 63;
    float inv = expf(-(float)(2 * j) * (1.0f / 128.0f) * logf(10000.0f));
    float ang = (float)t * inv;
    tab[i]              = cosf(ang);
    tab[T_SEQ * 64 + i] = sinf(ang);
}

// ---------------------------------------------------------------------------
// Convert fp32 inputs -> bf16
// ---------------------------------------------------------------------------
__global__ void convert_inputs(const float* __restrict__ x,  const float* __restrict__ wq,
                               const float* __restrict__ wk, const float* __restrict__ wv,
                               const float* __restrict__ wo,
                               unsigned short* __restrict__ xb,
                               unsigned short* __restrict__ wcat,
                               unsigned short* __restrict__ wob) {
    const int NX4 = (M_ROWS * HDIM) / 4;   // 4,194,304
    const int NW4 = (HDIM * HDIM) / 4;     // 1,048,576
    int i = blockIdx.x * blockDim.x + threadIdx.x;
    if (i >= NX4 + 4 * NW4) return;
    const float* src; unsigned short* dst; size_t off;
    if (i < NX4)                { src = x;  dst = xb;                      off = i; }
    else if (i < NX4 + NW4)     { src = wq; dst = wcat;                    off = i - NX4; }
    else if (i < NX4 + 2 * NW4) { src = wk; dst = wcat + HDIM * HDIM;      off = (size_t)i - NX4 - NW4; }
    else if (i < NX4 + 3 * NW4) { src = wv; dst = wcat + 2 * HDIM * HDIM;  off = (size_t)i - NX4 - 2 * NW4; }
    else                        { src = wo; dst = wob;                     off = (size_t)i - NX4 - 3 * NW4; }
    float4 v = *(const float4*)(src + 4 * off);
    ushort4 p;
    p.x = f2bf(v.x); p.y = f2bf(v.y); p.z = f2bf(v.z); p.w = f2bf(v.w);
    *(ushort4*)(dst + 4 * off) = p;
}

// ---------------------------------------------------------------------------
// RoPE in-place on bf16 Q,K, layout [B][nH][T][hd]. 4 d-pairs per thread.
// ---------------------------------------------------------------------------
__global__ void rope_bf16(unsigned short* __restrict__ Q, unsigned short* __restrict__ K,
                          const float* __restrict__ tab) {
    int i = blockIdx.x * blockDim.x + threadIdx.x;
    if (i >= BATCH * NH * T_SEQ * 16) return;
    int d4 = (i & 15) << 2;                  // 0..60
    int rrow = i >> 4;                       // over B*nH*T
    int t = rrow & (T_SEQ - 1);
    size_t base = (size_t)rrow * HD + d4;
    float4 c = *(const float4*)&tab[t * 64 + d4];
    float4 s = *(const float4*)&tab[T_SEQ * 64 + t * 64 + d4];

    ushort4 qa = *(ushort4*)&Q[base], qb = *(ushort4*)&Q[base + 64];
    ushort4 ka = *(ushort4*)&K[base], kb = *(ushort4*)&K[base + 64];
    ushort4 oqa, oqb, oka, okb;
    float a0, a1;
#define ROT(vec_a, vec_b, out_a, out_b, comp, cc, ss)                         \
    a0 = bf2f(vec_a.comp); a1 = bf2f(vec_b.comp);                             \
    out_a.comp = f2bf(a0 * cc - a1 * ss);                                     \
    out_b.comp = f2bf(a1 * cc + a0 * ss);
    ROT(qa, qb, oqa, oqb, x, c.x, s.x)  ROT(qa, qb, oqa, oqb, y, c.y, s.y)
    ROT(qa, qb, oqa, oqb, z, c.z, s.z)  ROT(qa, qb, oqa, oqb, w, c.w, s.w)
    ROT(ka, kb, oka, okb, x, c.x, s.x)  ROT(ka, kb, oka, okb, y, c.y, s.y)
    ROT(ka, kb, oka, okb, z, c.z, s.z)  ROT(ka, kb, oka, okb, w, c.w, s.w)
#undef ROT
    *(ushort4*)&Q[base]      = oqa;
    *(ushort4*)&Q[base + 64] = oqb;
    *(ushort4*)&K[base]      = oka;
    *(ushort4*)&K[base + 64] = okb;
}

// ---------------------------------------------------------------------------
// bf16 MFMA NT GEMM, 128x128 tile, BK=32, 4 waves (2x2), 16x16x32 MFMA.
// Double-buffered LDS + next-tile prefetch (T3-minimum, 1 barrier/step);
// coalesced staging via XOR-swizzled chunk order:
//   logical chunk (row, oct) stored at slot = row*4 + (oct ^ ((row>>1)&3))
// so 4 consecutive lanes fetch one row's contiguous 64B, and fragment
// ds_read_b128s stay <=2-way bank-aliased (free).
// XCD-aware blockIdx swizzle (T1): nwg % 8 == 0 for all our grids, so the
// remap flat -> (flat&7)*(nwg/8) + (flat>>3) is bijective; each XCD's L2
// then holds a contiguous band of m-rows (A-panel reuse).
// MODE 0: bf16 out, head-split: Q,K -> [b][h][t][d]; V -> [b][h][d][t].
// MODE 1: fp32 out, row-major C[M][Ncols].
// ---------------------------------------------------------------------------
template <int MODE>
__global__ __launch_bounds__(256) void gemm_bf16(
        const unsigned short* __restrict__ A,
        const unsigned short* __restrict__ W,
        void* __restrict__ Cv, int Ncols) {
    __shared__ __align__(16) unsigned short As[2][512][8];   // 8 KB / buf
    __shared__ __align__(16) unsigned short Bs[2][512][8];
    const int K = HDIM;
    const int tid = threadIdx.x;
    const int lane = tid & 63;
    const int wid = tid >> 6;
    const int wrow = wid >> 1, wcol = wid & 1;

    // XCD swizzle (bijective: grid counts are multiples of 8)
    const int nwg = gridDim.x * gridDim.y;
    int flat = blockIdx.y * gridDim.x + blockIdx.x;
    flat = (flat & 7) * (nwg >> 3) + (flat >> 3);
    const int m0 = (flat / gridDim.x) * 128;
    const int n0 = (flat % gridDim.x) * 128;

    f32x4 acc[4][4] = {};

    // staging: instr i: slot s = tid + i*256; row = s>>2;
    // logical oct = (s&3) ^ ((row>>1)&3); src = base + row*K + k0 + oct*8
    const int s0r = tid >> 2,          s0o = (tid & 3) ^ ((s0r >> 1) & 3);
    const int s1r = (tid + 256) >> 2,  s1o = ((tid + 256) & 3) ^ ((s1r >> 1) & 3);
    const unsigned short* gA0 = A + (size_t)(m0 + s0r) * K + s0o * 8;
    const unsigned short* gA1 = A + (size_t)(m0 + s1r) * K + s1o * 8;
    const unsigned short* gB0 = W + (size_t)(n0 + s0r) * K + s0o * 8;
    const unsigned short* gB1 = W + (size_t)(n0 + s1r) * K + s1o * 8;
    const int d0 = (0 * 256 + wid * 64) * 16;   // wave-uniform LDS dest (bytes)
    const int d1 = (1 * 256 + wid * 64) * 16;

    auto stage = [&](int buf, int k0) {
        char* ab = (char*)As + buf * 8192;
        char* bb = (char*)Bs + buf * 8192;
        __builtin_amdgcn_global_load_lds(GLOBAL_AS(gA0 + k0), LDS_AS(ab + d0), 16, 0, 0);
        __builtin_amdgcn_global_load_lds(GLOBAL_AS(gA1 + k0), LDS_AS(ab + d1), 16, 0, 0);
        __builtin_amdgcn_global_load_lds(GLOBAL_AS(gB0 + k0), LDS_AS(bb + d0), 16, 0, 0);
        __builtin_amdgcn_global_load_lds(GLOBAL_AS(gB1 + k0), LDS_AS(bb + d1), 16, 0, 0);
    };

    // fragment read offsets: row = wrow*64 + m*16 + (lane&15); oct = lane>>4
    // slot = row*4 + (oct ^ (((lane&15)>>1)&3))   (xor term m-invariant)
    const int xo = ((lane >> 4) ^ (((lane & 15) >> 1) & 3)) * 16;
    const int aF = (wrow * 64 + (lane & 15)) * 64 + xo;
    const int bF = (wcol * 64 + (lane & 15)) * 64 + xo;

    stage(0, 0);
    __syncthreads();

    for (int k0 = 0; k0 < K; k0 += 32) {
        const int cur = (k0 >> 5) & 1;
        if (k0 + 32 < K) stage(cur ^ 1, k0 + 32);

        const char* ab = (const char*)As + cur * 8192;
        const char* bb = (const char*)Bs + cur * 8192;
        bf16x8 fa[4], fb[4];
#pragma unroll
        for (int m = 0; m < 4; ++m) fa[m] = *(const bf16x8*)(ab + aF + m * 1024);
#pragma unroll
        for (int n = 0; n < 4; ++n) fb[n] = *(const bf16x8*)(bb + bF + n * 1024);
#pragma unroll
        for (int m = 0; m < 4; ++m)
#pragma unroll
            for (int n = 0; n < 4; ++n)
                acc[m][n] = __builtin_amdgcn_mfma_f32_16x16x32_bf16(fa[m], fb[n], acc[m][n], 0, 0, 0);
        __syncthreads();
    }

    // epilogue: C/D layout col = lane&15, row = (lane>>4)*4 + r
    const int colBase = n0 + wcol * 64 + (lane & 15);
    const int rowBase = m0 + wrow * 64 + (lane >> 4) * 4;
#pragma unroll
    for (int m = 0; m < 4; ++m) {
        int row0 = rowBase + m * 16;                  // multiple of 4
#pragma unroll
        for (int n = 0; n < 4; ++n) {
            int col = colBase + n * 16;
            if (MODE == 1) {
                float* C = (float*)Cv;
#pragma unroll
                for (int r = 0; r < 4; ++r)
                    C[(size_t)(row0 + r) * Ncols + col] = acc[m][n][r];
            } else {
                unsigned short* Cb = (unsigned short*)Cv;
                int tensor = col >> 11;
                int head = (col >> 7) & 15;
                int d = col & (HD - 1);
                int b = row0 >> 11;
                int t0 = row0 & (T_SEQ - 1);
                if (tensor == 2) {                    // V transposed: [b][h][d][t]
                    ushort4 pvv;
                    pvv.x = f2bf(acc[m][n][0]); pvv.y = f2bf(acc[m][n][1]);
                    pvv.z = f2bf(acc[m][n][2]); pvv.w = f2bf(acc[m][n][3]);
                    *(ushort4*)&Cb[2 * QSZ + ((size_t)(b * NH + head) * HD + d) * T_SEQ + t0] = pvv;
                } else {                              // Q/K: [b][h][t][d]
#pragma unroll
                    for (int r = 0; r < 4; ++r)
                        Cb[(size_t)tensor * QSZ +
                           ((size_t)(b * NH + head) * T_SEQ + (t0 + r)) * HD + d] =
                            f2bf(acc[m][n][r]);
                }
            }
        }
    }
}

// ---------------------------------------------------------------------------
// bf16 MFMA flash attention, causal. Grid (T/64, B*nH), 256 thr = 4 waves.
// Each wave owns 16 q rows (w*16..+16) x full d. Swapped QK^T (mfma(K,Q)) so
// each lane holds its q-row's 16 k-values -> in-register online softmax
// (2x shfl_xor reduce), no S LDS. Q hoisted to registers. K/V double-buffered
// with next-tile prefetch; ONE barrier per kv-tile. P is wave-private LDS.
// LDS K/V chunks XOR-swizzled (written via pre-swizzled global source).
// XCD swizzle groups 8 consecutive bh per XCD (K/V panel L2 reuse).
// LPT dispatch: qt reversed so the heaviest causal blocks (qt=31, 32 kv-tiles)
// launch FIRST and light blocks backfill the tail (bijective, perf-only).
// ---------------------------------------------------------------------------
__global__ __launch_bounds__(256) void flash_mfma(
        const unsigned short* __restrict__ Qg, const unsigned short* __restrict__ Kg,
        const unsigned short* __restrict__ Vg, unsigned short* __restrict__ Og) {
    __shared__ __align__(16) unsigned short Ks[2][64][16][8];  // slot=row*16+(dseg^(row&7))
    __shared__ __align__(16) unsigned short Vs[2][128][8][8];  // slot=d*8+(tseg^(d&7))
    __shared__ __align__(16) unsigned short Ps[4][8][16][8];   // [wave][k-oct][q][8]

    const int tid = threadIdx.x;
    const int lane = tid & 63;
    const int w = tid >> 6;
    const int g = lane >> 4;          // 0..3
    const int l15 = lane & 15;
    const int xk = lane & 7;

    // XCD swizzle (2048 blocks, bijective) + LPT (heavy qt first)
    const int nwg = gridDim.x * gridDim.y;
    int flat = blockIdx.y * gridDim.x + blockIdx.x;
    flat = (flat & 7) * (nwg >> 3) + (flat >> 3);
    const int qt = (gridDim.x - 1) - (flat % gridDim.x);
    const int bh = flat / gridDim.x;
    const int q0 = qt * 64;
    const size_t bho = (size_t)bh * T_SEQ * HD;
    const unsigned short* Kp = Kg + bho;
    const unsigned short* Vp = Vg + bho;                       // [d][t]

    // hoist Q fragments (loop-invariant): q row = q0 + w*16 + l15
    bf16x8 qfrag[4];
    {
        const unsigned short* Qp = Qg + bho + (size_t)(q0 + w * 16 + l15) * HD + g * 8;
        qfrag[0] = *(const bf16x8*)(Qp);
        qfrag[1] = *(const bf16x8*)(Qp + 32);
        qfrag[2] = *(const bf16x8*)(Qp + 64);
        qfrag[3] = *(const bf16x8*)(Qp + 96);
    }

    // staging coords (per-lane global source, pre-swizzled; LDS dest linear)
    int krow[4], kcol[4], vd[4], vt[4];
#pragma unroll
    for (int i = 0; i < 4; ++i) {
        int s = tid + i * 256;
        int r = s >> 4, dp = s & 15;
        krow[i] = r; kcol[i] = (dp ^ (r & 7)) * 8;
        int d = s >> 3, tp = s & 7;
        vd[i] = d; vt[i] = (tp ^ (d & 7)) * 8;
    }

    auto stagekv = [&](int buf, int kv) {
        char* kb = (char*)Ks + buf * 16384;
        char* vb = (char*)Vs + buf * 16384;
#pragma unroll
        for (int i = 0; i < 4; ++i) {
            __builtin_amdgcn_global_load_lds(
                GLOBAL_AS(Kp + (size_t)(kv + krow[i]) * HD + kcol[i]),
                LDS_AS(kb + (i * 256 + w * 64) * 16), 16, 0, 0);
            __builtin_amdgcn_global_load_lds(
                GLOBAL_AS(Vp + (size_t)vd[i] * T_SEQ + kv + vt[i]),
                LDS_AS(vb + (i * 256 + w * 64) * 16), 16, 0, 0);
        }
    };

    f32x4 oacc[8] = {};
    float m_run = -3.0e38f, l_run = 0.0f;
    const float scale = 0.08838834764831845f;   // 1/sqrt(128)
    const int qrow_s = q0 + w * 16 + l15;       // my softmax q row

    stagekv(0, 0);
    __syncthreads();

    for (int t = 0; t <= qt; ++t) {
        const int cur = t & 1;
        const int kv0 = t * 64;
        if (t < qt) stagekv(cur ^ 1, kv0 + 64);

        // QK^T swapped: sacc[kt] rows = k (kt*16 + g*4 + r), cols = q (l15)
        const char* kbase = (const char*)Ks + cur * 16384 + l15 * 256;
        f32x4 sacc[4] = {};
#pragma unroll
        for (int ds = 0; ds < 4; ++ds) {
            bf16x8 kf[4];
#pragma unroll
            for (int kt = 0; kt < 4; ++kt)
                kf[kt] = *(const bf16x8*)(kbase + kt * 4096 + ((ds * 4 + g) ^ xk) * 16);
#pragma unroll
            for (int kt = 0; kt < 4; ++kt)
                sacc[kt] = __builtin_amdgcn_mfma_f32_16x16x32_bf16(kf[kt], qfrag[ds], sacc[kt], 0, 0, 0);
        }

        // scale + causal mask + in-register online softmax
        const bool diag = (t == qt);
        float pv[16];
        float pmax = -3.0e38f;
#pragma unroll
        for (int kt = 0; kt < 4; ++kt)
#pragma unroll
            for (int r = 0; r < 4; ++r) {
                float v = sacc[kt][r] * scale;
                if (diag && (kv0 + kt * 16 + g * 4 + r > qrow_s)) v = -1.0e30f;
                pv[kt * 4 + r] = v;
                pmax = fmaxf(pmax, v);
            }
        pmax = fmaxf(pmax, __shfl_xor(pmax, 16));
        pmax = fmaxf(pmax, __shfl_xor(pmax, 32));
        const float mnew = fmaxf(m_run, pmax);
        const float fac = __expf(m_run - mnew);
        float psum = 0.0f;
#pragma unroll
        for (int j = 0; j < 16; ++j) { pv[j] = __expf(pv[j] - mnew); psum += pv[j]; }
        psum += __shfl_xor(psum, 16);
        psum += __shfl_xor(psum, 32);
        l_run = l_run * fac + psum;
        m_run = mnew;

        // write P (wave-private): k = kt*16+g*4+r -> oct kt*2+(g>>1), elem (g&1)*4+r
        {
            char* pbase = (char*)Ps + w * 2048 + l15 * 16 + (g & 1) * 8;
#pragma unroll
            for (int kt = 0; kt < 4; ++kt) {
                ushort4 pk;
                pk.x = f2bf(pv[kt * 4 + 0]); pk.y = f2bf(pv[kt * 4 + 1]);
                pk.z = f2bf(pv[kt * 4 + 2]); pk.w = f2bf(pv[kt * 4 + 3]);
                *(ushort4*)(pbase + (kt * 2 + (g >> 1)) * 256) = pk;
            }
        }
        asm volatile("s_waitcnt lgkmcnt(0)" ::: "memory");   // P writes visible to own wave

        // rescale O by fac of row q = g*4 + r (broadcast from lane q)
        float facv[4];
#pragma unroll
        for (int r = 0; r < 4; ++r) facv[r] = __shfl(fac, g * 4 + r);
#pragma unroll
        for (int dt = 0; dt < 8; ++dt)
#pragma unroll
            for (int r = 0; r < 4; ++r) oacc[dt][r] *= facv[r];

        // PV: O[q][d] += P[q][k] V[k][d]
        const char* vbase = (const char*)Vs + cur * 16384 + l15 * 128;
        const char* pread = (const char*)Ps + w * 2048 + l15 * 16;
#pragma unroll
        for (int ks = 0; ks < 2; ++ks) {
            bf16x8 pa = *(const bf16x8*)(pread + (ks * 4 + g) * 256);
#pragma unroll
            for (int dt = 0; dt < 8; ++dt) {
                bf16x8 vb = *(const bf16x8*)(vbase + dt * 2048 + ((ks * 4 + g) ^ xk) * 16);
                oacc[dt] = __builtin_amdgcn_mfma_f32_16x16x32_bf16(pa, vb, oacc[dt], 0, 0, 0);
            }
        }
        __syncthreads();   // K/V buf reuse + drains prefetch (vmcnt0 in barrier)
    }

    // normalize + write [b][t][h*128+d]
    float inv = 1.0f / l_run;
    float invv[4];
#pragma unroll
    for (int r = 0; r < 4; ++r) invv[r] = __shfl(inv, g * 4 + r);
    const int b = bh >> 4, h = bh & 15;
#pragma unroll
    for (int dt = 0; dt < 8; ++dt) {
        int d = dt * 16 + l15;
#pragma unroll
        for (int r = 0; r < 4; ++r) {
            int q = q0 + w * 16 + g * 4 + r;
            Og[((size_t)b * T_SEQ + q) * HDIM + h * HD + d] = f2bf(oacc[dt][r] * invv[r]);
        }
    }
}

// ---------------------------------------------------------------------------
// launch
// ---------------------------------------------------------------------------
extern "C" void kernel_launch(void* const* d_in, const int* in_sizes, int n_in,
                              void* d_out, int out_size, void* d_ws, size_t ws_size,
                              hipStream_t stream) {
    const float* x  = (const float*)d_in[0];
    const float* Wq = (const float*)d_in[1];
    const float* Wk = (const float*)d_in[2];
    const float* Wv = (const float*)d_in[3];
    const float* Wo = (const float*)d_in[4];
    float* out = (float*)d_out;

    char* w = (char*)d_ws;
    float* tab = (float*)w;                                        // 1 MB
    unsigned short* xb   = (unsigned short*)(w + (size_t)2 * T_SEQ * 64 * sizeof(float));
    unsigned short* wcat = xb + (size_t)M_ROWS * HDIM;             // [6144][2048]
    unsigned short* wob  = wcat + (size_t)3 * HDIM * HDIM;
    unsigned short* qkv  = wob + (size_t)HDIM * HDIM;              // Q,K [b][h][t][d]; Vt [b][h][d][t]
    unsigned short* aob  = qkv + 3 * QSZ;                          // [8192][2048]

    rope_table_kernel<<<512, 256, 0, stream>>>(tab);

    int nconv = (M_ROWS * HDIM) / 4 + HDIM * HDIM;
    convert_inputs<<<(nconv + 255) / 256, 256, 0, stream>>>(x, Wq, Wk, Wv, Wo, xb, wcat, wob);

    dim3 gqkv(3 * HDIM / 128, M_ROWS / 128);                       // (48, 64) = 3072 wgs
    gemm_bf16<0><<<gqkv, 256, 0, stream>>>(xb, wcat, (void*)qkv, 3 * HDIM);

    int rtot = BATCH * NH * T_SEQ * 16;
    rope_bf16<<<(rtot + 255) / 256, 256, 0, stream>>>(qkv, qkv + QSZ, tab);

    dim3 fgrid(T_SEQ / 64, BATCH * NH);                            // (32, 64) = 2048 wgs
    flash_mfma<<<fgrid, 256, 0, stream>>>(qkv, qkv + QSZ, qkv + 2 * QSZ, aob);

    dim3 go(HDIM / 128, M_ROWS / 128);                             // (16, 64) = 1024 wgs
    gemm_bf16<1><<<go, 256, 0, stream>>>(aob, wob, (void*)out, HDIM);
}